// Round 7
// baseline (142.231 us; speedup 1.0000x reference)
//
#include <hip/hip_runtime.h>
#include <math.h>

#ifndef __has_builtin
#define __has_builtin(x) 0
#endif

#define NPTS   131072
#define FCH    16
#define CSND   343.0f
#define PB     16           // points per pass (halved)
#define BLOCK  128          // 2 waves
#define GRID   2048         // 4 passes/block exactly; ~5 WG/CU resident (28KB LDS)
#define NBLK   (NPTS / PB)  // 8192

typedef _Float16 half8 __attribute__((ext_vector_type(8)));
typedef _Float16 half2v __attribute__((ext_vector_type(2)));
typedef float    f32x4 __attribute__((ext_vector_type(4)));

static __device__ __forceinline__ half2v pk2h(float a, float b) {
#if __has_builtin(__builtin_amdgcn_cvt_pkrtz)
  // builtin returns __fp16 ext_vector(2); bit-identical to half2v -> bit_cast
  return __builtin_bit_cast(half2v, __builtin_amdgcn_cvt_pkrtz(a, b));
#else
  half2v v; v[0] = (_Float16)a; v[1] = (_Float16)b;
  return v;
#endif
}
static __device__ __forceinline__ unsigned pack2(float a, float b) {
  return __builtin_bit_cast(unsigned, pk2h(a, b));
}
#define U32(h) __builtin_bit_cast(unsigned, (h))

// tanh(x) = 1 - 2/(e^{2x}+1): trans exp + rcp, monotone-correct at +/-inf.
static __device__ __forceinline__ float mytanh(float x) {
#if __has_builtin(__builtin_amdgcn_exp2f)
  float e = __builtin_amdgcn_exp2f(2.885390082f * x);   // 2*log2(e)*x
#else
  float e = __expf(2.0f * x);
#endif
  return fmaf(-2.0f, __builtin_amdgcn_rcpf(e + 1.0f), 1.0f);
}

// SMALL-WG variant of the round-6 kernel (which measured 59.4us, spill-free):
// PB 32->16, BLOCK 256->128 (2 waves). All per-point pipe costs invariant
// (per wave-pass: 28 ds_read_b128, 88 MFMA, 16+16 tanh/thread -- identical to
// round 6), but LDS/WG = 20KB s_A + 8KB s_HG = 28KB -> 5 WG/CU = 10 waves/CU
// (2.5/SIMD) with 5 independently-phased WGs: one WG's A/C VALU overlaps
// another's B/D MFMA+LDS. Round 6 had 2 waves/SIMD both usually at the same
// phase -> wave-serial execution (measured ~9k cyc/SIMD/pass-pair vs ~6k
// serial-issue estimate). Registers identical (~124; budget 256 at (128,2)).
// LDS map (PB=16): s_A[80][64] dw: A f16, rows R = v*16+p (v=0..4:
//   h1,d0,d1,d2,c1; p=0..15), chunk c (4dw = 8 units) at (c ^ p).
//   s_HG[16][128] dw: point p: h2 [p*128..+63], G [+64..+127]; dword
//   q = 32*nh+16*pr+col holds pack2(t4=2pr,2pr+1), chunk-swizzled (cq ^ p);
//   w3f rows j-permuted to match (PB-independent formula).
// Wave roles: wave w = nh (n-half / re-im tile); m-tile = all 16 points.
// Loop: [D(i-1)] A(i) |b1| B(i),C(i) |b2|  (2 barriers/pass; D overlaps A).
// GRID=2048: exactly 4 passes/block, backfill scheduling adds natural phase
// diversity; small s_sleep stagger de-convoys each CU's initial cohort.

__global__ __launch_bounds__(BLOCK, 2) void helmholtz_kernel(
    const float* __restrict__ x,      // [N,3]
    const float* __restrict__ omega,  // [16]
    const float* __restrict__ W1,     // [3,128]
    const float* __restrict__ b1,     // [128]
    const float* __restrict__ W2,     // [128,128]
    const float* __restrict__ b2,     // [128]
    const float* __restrict__ W3,     // [128,32]
    const float* __restrict__ b3,     // [32]
    float* __restrict__ out)
{
  __shared__ unsigned s_A[80 * 64];    // 20 KB
  __shared__ unsigned s_HG[16 * 128];  // 8 KB

  // ---- one-time stagger: de-convoy the ~5 WGs sharing each CU ----
  {
    int k = (blockIdx.x >> 8) % 5;     // initial cohort on a CU: {i+256m}
    for (int i = 0; i < k; i++) __builtin_amdgcn_s_sleep(32);  // ~2k cyc each
  }

  const int tid  = threadIdx.x;
  const int w    = tid >> 6;   // wave 0..1
  const int l    = tid & 63;
  const int col  = l & 15;
  const int quad = l >> 4;
  const int nh   = w;          // n-half (B); re/im tile (D)

  // ---- phase A task: points pA, pA+8; units 8g..8g+7 ----
  const int pA = tid >> 4;     // 0..7
  const int g  = tid & 15;
  float wx[8], wy[8], wz[8], bB[8];
#pragma unroll
  for (int u = 0; u < 8; u++) {
    int unit = 8 * g + u;
    wx[u] = W1[unit]; wy[u] = W1[128 + unit]; wz[u] = W1[256 + unit];
    bB[u] = b1[unit];
  }
  // packed W1 copies + folded -2*wq (computed once)
  half2v wxp[4], wyp[4], wzp[4], wqm[4];
#pragma unroll
  for (int j = 0; j < 4; j++) {
    wxp[j] = pk2h(wx[2*j], wx[2*j+1]);
    wyp[j] = pk2h(wy[2*j], wy[2*j+1]);
    wzp[j] = pk2h(wz[2*j], wz[2*j+1]);
    float wq0 = fmaf(wx[2*j],   wx[2*j],   fmaf(wy[2*j],   wy[2*j],   wz[2*j]   * wz[2*j]));
    float wq1 = fmaf(wx[2*j+1], wx[2*j+1], fmaf(wy[2*j+1], wy[2*j+1], wz[2*j+1] * wz[2*j+1]));
    wqm[j] = pk2h(-2.0f * wq0, -2.0f * wq1);
  }
  const half2v hone = {(_Float16)1.0f, (_Float16)1.0f};

  // ---- W2^T fragments: 4 n-tiles (cols 64*nh + 16*t4 + col), 64 VGPRs ----
  half8 w2f[4][4];
#pragma unroll
  for (int t4 = 0; t4 < 4; t4++) {
    const int n = 64 * nh + 16 * t4 + col;
#pragma unroll
    for (int ks = 0; ks < 4; ks++) {
      half8 f;
#pragma unroll
      for (int j8 = 0; j8 < 8; j8++)
        f[j8] = (_Float16)W2[(ks * 32 + (quad << 3) + j8) * 128 + n];
      w2f[t4][ks] = f;
    }
  }
  // ---- W3^T fragment, j-permuted to match HG layout (16 VGPRs) ----
  half8 w3f[4];
#pragma unroll
  for (int ks = 0; ks < 4; ks++) {
    half8 f;
#pragma unroll
    for (int j8 = 0; j8 < 8; j8++) {
      int kap = ks * 32 + (quad << 3) + j8;
      int q   = kap >> 1;
      int j   = 64 * (q >> 5) + 32 * ((q >> 4) & 1) + 16 * (kap & 1) + (q & 15);
      f[j8] = (_Float16)W3[j * 32 + 16 * nh + col];
    }
    w3f[ks] = f;
  }

  float b2r[4];
#pragma unroll
  for (int t4 = 0; t4 < 4; t4++) b2r[t4] = b2[64 * nh + 16 * t4 + col];
  float k2v = 0.0f;
  if (col >= 1) {
    float om = omega[col] * (1.0f / CSND);
    k2v = om * om;
  }
  const float b3v = b3[16 * nh + col];

  float wsum = 0.0f;
  float xr[2][3];

  auto loadX = [&](int blk) {
    const float* xb = x + (size_t)blk * PB * 3;
#pragma unroll
    for (int hp = 0; hp < 2; hp++) {
      int p = pA + 8 * hp;
      xr[hp][0] = xb[3 * p]; xr[hp][1] = xb[3 * p + 1]; xr[hp][2] = xb[3 * p + 2];
    }
  };

  auto phaseA = [&]() {
#pragma unroll
    for (int hp = 0; hp < 2; hp++) {
      int p = pA + 8 * hp;
      const int cbase = (g ^ p) << 2;
      float x0 = xr[hp][0], x1 = xr[hp][1], x2 = xr[hp][2];
      float t[8];
#pragma unroll
      for (int u = 0; u < 8; u++) {
        float z = fmaf(x0, wx[u], fmaf(x1, wy[u], fmaf(x2, wz[u], bB[u])));
        t[u] = mytanh(z);
      }
      half2v tp[4], sp[4];
#pragma unroll
      for (int j = 0; j < 4; j++) {
        tp[j] = pk2h(t[2*j], t[2*j+1]);
        sp[j] = hone - tp[j] * tp[j];           // v_pk_fma path
      }
      uint4 q;
      q = make_uint4(U32(tp[0]), U32(tp[1]), U32(tp[2]), U32(tp[3]));
      *(uint4*)&s_A[(p)       * 64 + cbase] = q;
      q = make_uint4(U32(sp[0]*wxp[0]), U32(sp[1]*wxp[1]),
                     U32(sp[2]*wxp[2]), U32(sp[3]*wxp[3]));
      *(uint4*)&s_A[(16 + p)  * 64 + cbase] = q;
      q = make_uint4(U32(sp[0]*wyp[0]), U32(sp[1]*wyp[1]),
                     U32(sp[2]*wyp[2]), U32(sp[3]*wyp[3]));
      *(uint4*)&s_A[(32 + p)  * 64 + cbase] = q;
      q = make_uint4(U32(sp[0]*wzp[0]), U32(sp[1]*wzp[1]),
                     U32(sp[2]*wzp[2]), U32(sp[3]*wzp[3]));
      *(uint4*)&s_A[(48 + p)  * 64 + cbase] = q;
      half2v cp[4];
#pragma unroll
      for (int j = 0; j < 4; j++) cp[j] = (tp[j] * sp[j]) * wqm[j];
      q = make_uint4(U32(cp[0]), U32(cp[1]), U32(cp[2]), U32(cp[3]));
      *(uint4*)&s_A[(64 + p)  * 64 + cbase] = q;
    }
  };

  auto phaseDE = [&]() {
    const int pbase = col * 128;   // point row; (row&15)=col swizzle key
    f32x4 dy = (f32x4){0.0f, 0.0f, 0.0f, 0.0f};
    f32x4 dl = (f32x4){0.0f, 0.0f, 0.0f, 0.0f};
#pragma unroll
    for (int ks = 0; ks < 4; ks++) {
      int pos = ((((ks << 2) + quad) ^ col) << 2);
      half8 afy = *(const half8*)&s_HG[pbase + pos];
      half8 afl = *(const half8*)&s_HG[pbase + 64 + pos];
      dy = __builtin_amdgcn_mfma_f32_16x16x32_f16(afy, w3f[ks], dy, 0, 0, 0);
      dl = __builtin_amdgcn_mfma_f32_16x16x32_f16(afl, w3f[ks], dl, 0, 0, 0);
    }
    if (col >= 1) {
#pragma unroll
      for (int r = 0; r < 4; r++) {
        float yv  = dy[r] + b3v;
        float res = fmaf(k2v, yv, dl[r]);
        wsum += res * res;
      }
    }
  };

  // ---- main loop: [D(i-1)] A(i) |b1| B(i),C(i) |b2| ----
  loadX(blockIdx.x);
  bool first = true;
  for (int blk = blockIdx.x; blk < NBLK; blk += gridDim.x) {
    if (!first) phaseDE();          // D(i-1): reads s_HG (pre-b1)
    first = false;
    phaseA();                       // writes s_A
    __syncthreads();                // b1

    int nblk = blk + (int)gridDim.x;
    if (nblk < NBLK) loadX(nblk);   // prefetch x for next pass

    // ---- B(i): m=16 x n-half GEMM; per-d collapse caps transient regs ----
    f32x4 bsum[4], acch[4], accc[4];
#pragma unroll
    for (int t4 = 0; t4 < 4; t4++)
      bsum[t4] = (f32x4){0.0f, 0.0f, 0.0f, 0.0f};
#pragma unroll
    for (int d = 0; d < 3; d++) {
      f32x4 accd[4];
#pragma unroll
      for (int t4 = 0; t4 < 4; t4++)
        accd[t4] = (f32x4){0.0f, 0.0f, 0.0f, 0.0f};
      const int rb = ((d + 1) * 16 + col) * 64;
#pragma unroll
      for (int ks = 0; ks < 4; ks++) {
        half8 af = *(const half8*)&s_A[rb + ((((ks << 2) + quad) ^ col) << 2)];
        accd[0] = __builtin_amdgcn_mfma_f32_16x16x32_f16(af, w2f[0][ks], accd[0], 0, 0, 0);
        accd[1] = __builtin_amdgcn_mfma_f32_16x16x32_f16(af, w2f[1][ks], accd[1], 0, 0, 0);
        accd[2] = __builtin_amdgcn_mfma_f32_16x16x32_f16(af, w2f[2][ks], accd[2], 0, 0, 0);
        accd[3] = __builtin_amdgcn_mfma_f32_16x16x32_f16(af, w2f[3][ks], accd[3], 0, 0, 0);
      }
#pragma unroll
      for (int t4 = 0; t4 < 4; t4++)
        bsum[t4] += accd[t4] * accd[t4];
    }
#pragma unroll
    for (int t4 = 0; t4 < 4; t4++) {
      acch[t4] = (f32x4){0.0f, 0.0f, 0.0f, 0.0f};
      accc[t4] = (f32x4){0.0f, 0.0f, 0.0f, 0.0f};
    }
    {
      const int rb0 = (col) * 64;          // h1 rows (v=0)
      const int rb4 = (64 + col) * 64;     // c1 rows (v=4)
#pragma unroll
      for (int ks = 0; ks < 4; ks++) {
        int pos = ((((ks << 2) + quad) ^ col) << 2);
        half8 afh = *(const half8*)&s_A[rb0 + pos];
        half8 afc = *(const half8*)&s_A[rb4 + pos];
        acch[0] = __builtin_amdgcn_mfma_f32_16x16x32_f16(afh, w2f[0][ks], acch[0], 0, 0, 0);
        acch[1] = __builtin_amdgcn_mfma_f32_16x16x32_f16(afh, w2f[1][ks], acch[1], 0, 0, 0);
        acch[2] = __builtin_amdgcn_mfma_f32_16x16x32_f16(afh, w2f[2][ks], acch[2], 0, 0, 0);
        acch[3] = __builtin_amdgcn_mfma_f32_16x16x32_f16(afh, w2f[3][ks], acch[3], 0, 0, 0);
        accc[0] = __builtin_amdgcn_mfma_f32_16x16x32_f16(afc, w2f[0][ks], accc[0], 0, 0, 0);
        accc[1] = __builtin_amdgcn_mfma_f32_16x16x32_f16(afc, w2f[1][ks], accc[1], 0, 0, 0);
        accc[2] = __builtin_amdgcn_mfma_f32_16x16x32_f16(afc, w2f[2][ks], accc[2], 0, 0, 0);
        accc[3] = __builtin_amdgcn_mfma_f32_16x16x32_f16(afc, w2f[3][ks], accc[3], 0, 0, 0);
      }
    }

    // ---- C(i): layer-2 elementwise; paired-dword writes into permuted HG ----
#pragma unroll
    for (int r = 0; r < 4; r++) {
      int p = (quad << 2) + r;             // point 0..15
      float t2[4], gg[4];
#pragma unroll
      for (int t4 = 0; t4 < 4; t4++) {
        float z2 = acch[t4][r] + b2r[t4];
        float t  = mytanh(z2);
        float s2 = 1.0f - t * t;
        t2[t4] = t;
        gg[t4] = s2 * (accc[t4][r] - 2.0f * t * bsum[t4][r]);
      }
      int pb = p * 128;
#pragma unroll
      for (int pr = 0; pr < 2; pr++) {
        int q   = 32 * nh + 16 * pr + col;
        int pos = (((q >> 2) ^ p) << 2) + (q & 3);
        s_HG[pb + pos]      = pack2(t2[2 * pr], t2[2 * pr + 1]);
        s_HG[pb + 64 + pos] = pack2(gg[2 * pr], gg[2 * pr + 1]);
      }
    }
    __syncthreads();                // b2
  }
  phaseDE();                        // epilogue D for the final pass

  // ---- final: wave reduce, one atomic per wave ----
#pragma unroll
  for (int off = 32; off > 0; off >>= 1)
    wsum += __shfl_down(wsum, off, 64);
  if (l == 0)
    atomicAdd(out, wsum * (1.0f / ((float)NPTS * (float)(FCH - 1))));
}

extern "C" void kernel_launch(void* const* d_in, const int* in_sizes, int n_in,
                              void* d_out, int out_size, void* d_ws, size_t ws_size,
                              hipStream_t stream) {
  const float* x     = (const float*)d_in[0];
  const float* omega = (const float*)d_in[1];
  const float* W1    = (const float*)d_in[2];
  const float* b1    = (const float*)d_in[3];
  const float* W2    = (const float*)d_in[4];
  const float* b2    = (const float*)d_in[5];
  const float* W3    = (const float*)d_in[6];
  const float* b3    = (const float*)d_in[7];
  float* out = (float*)d_out;

  (void)hipMemsetAsync(out, 0, sizeof(float), stream);
  helmholtz_kernel<<<GRID, BLOCK, 0, stream>>>(x, omega, W1, b1, W2, b2, W3, b3, out);
}

// Round 8
// 135.763 us; speedup vs baseline: 1.0476x; 1.0476x over previous
//
#include <hip/hip_runtime.h>
#include <math.h>

#ifndef __has_builtin
#define __has_builtin(x) 0
#endif

#define NPTS   131072
#define FCH    16
#define CSND   343.0f
#define PB     32           // points per pass
#define BLOCK  256          // 4 waves
#define GRID   1024         // 4 WG/CU * 256 CUs, persistent (4 passes/block)
#define NBLK   (NPTS / PB)  // 4096

typedef _Float16 half8 __attribute__((ext_vector_type(8)));
typedef _Float16 half2v __attribute__((ext_vector_type(2)));
typedef float    f32x4 __attribute__((ext_vector_type(4)));

static __device__ __forceinline__ half2v pk2h(float a, float b) {
#if __has_builtin(__builtin_amdgcn_cvt_pkrtz)
  // builtin returns __fp16 ext_vector(2); bit-identical to half2v -> bit_cast
  return __builtin_bit_cast(half2v, __builtin_amdgcn_cvt_pkrtz(a, b));
#else
  half2v v; v[0] = (_Float16)a; v[1] = (_Float16)b;
  return v;
#endif
}
static __device__ __forceinline__ unsigned pack2(float a, float b) {
  return __builtin_bit_cast(unsigned, pk2h(a, b));
}
#define U32(h) __builtin_bit_cast(unsigned, (h))

// tanh(x) = 1 - 2/(e^{2x}+1): exp+rcp on trans pipe, monotone at +/-inf.
static __device__ __forceinline__ float mytanh(float x) {
#if __has_builtin(__builtin_amdgcn_exp2f)
  float e = __builtin_amdgcn_exp2f(2.885390082f * x);   // 2*log2(e)*x
#else
  float e = __expf(2.0f * x);
#endif
  return fmaf(-2.0f, __builtin_amdgcn_rcpf(e + 1.0f), 1.0f);
}

// ROUND-6 body (59.4us, spill-free, VGPR=124 at (256,2)) with the HG buffer
// ALIASED into s_A: LDS 56KB -> 40KB/WG -> 4 WG/CU (160/40) by LDS, and 4
// waves/SIMD by VGPR (124 <= 128) -- residency doubles to 16 waves/CU with
// ZERO allocator pressure (launch_bounds stays (256,2): min-waves is a
// regalloc promise, not a residency cap; round 1's spills came from the
// (256,4) hard cap on a fatter body, not from this structure).
// Round-7 lesson: small WGs do NOT buy residency (occupancy stayed ~15%);
// this keeps BLOCK=256/PB=32 and buys residency with LDS instead.
// Cost: 4-barrier pass A|b1|B|b2|C|b3|D|b4 (alias kills D||A overlap);
// 4 phase-staggered WGs/CU provide the cross-WG overlap instead.
// LDS map: s_A[160][64] dw (40KB): A f16, rows R = v*32+p (v=0..4:
//   h1,d0,d1,d2,c1; p=0..31), chunk c (4dw = 8 units) at (c ^ (R&15)).
//   s_HG ALIAS = s_A dwords [0..4096): point p block p*128: h2 [0..63],
//   G [64..127]; dword q = 32*nh+16*pr+col holds pack2(2pr,2pr+1),
//   chunk-swizzled (cq ^ (p&15)); w3f rows j-permuted to match. Aliasing
//   legal: C reads only registers; s_A fully dead after B's last ds_read.
// Packed-f16 phase A and per-direction accd collapse kept from round 6.

__global__ __launch_bounds__(BLOCK, 2) void helmholtz_kernel(
    const float* __restrict__ x,      // [N,3]
    const float* __restrict__ omega,  // [16]
    const float* __restrict__ W1,     // [3,128]
    const float* __restrict__ b1,     // [128]
    const float* __restrict__ W2,     // [128,128]
    const float* __restrict__ b2,     // [128]
    const float* __restrict__ W3,     // [128,32]
    const float* __restrict__ b3,     // [32]
    float* __restrict__ out)
{
  __shared__ unsigned s_A[160 * 64];   // 40 KB; s_HG aliases dwords [0..4096)

  // ---- one-time quarter-pass stagger: de-convoy the 4 WGs per CU ----
  {
    int k = (blockIdx.x >> 8) & 3;     // co-resident cohort on a CU
    for (int i = 0; i < k; i++) __builtin_amdgcn_s_sleep(63);  // ~4k cyc each
  }

  const int tid  = threadIdx.x;
  const int w    = tid >> 6;   // wave 0..3
  const int l    = tid & 63;
  const int col  = l & 15;
  const int quad = l >> 4;
  const int ph   = w >> 1;     // point-half (B and D m-tile)
  const int nh   = w & 1;      // n-half (B); re/im tile (D)

  // ---- phase A task: points pA, pA+16; units 8g..8g+7 ----
  const int pA = tid >> 4;
  const int g  = tid & 15;
  float wx[8], wy[8], wz[8], bB[8];
#pragma unroll
  for (int u = 0; u < 8; u++) {
    int unit = 8 * g + u;
    wx[u] = W1[unit]; wy[u] = W1[128 + unit]; wz[u] = W1[256 + unit];
    bB[u] = b1[unit];
  }
  // packed W1 copies + folded -2*wq (computed once)
  half2v wxp[4], wyp[4], wzp[4], wqm[4];
#pragma unroll
  for (int j = 0; j < 4; j++) {
    wxp[j] = pk2h(wx[2*j], wx[2*j+1]);
    wyp[j] = pk2h(wy[2*j], wy[2*j+1]);
    wzp[j] = pk2h(wz[2*j], wz[2*j+1]);
    float wq0 = fmaf(wx[2*j],   wx[2*j],   fmaf(wy[2*j],   wy[2*j],   wz[2*j]   * wz[2*j]));
    float wq1 = fmaf(wx[2*j+1], wx[2*j+1], fmaf(wy[2*j+1], wy[2*j+1], wz[2*j+1] * wz[2*j+1]));
    wqm[j] = pk2h(-2.0f * wq0, -2.0f * wq1);
  }
  const half2v hone = {(_Float16)1.0f, (_Float16)1.0f};

  // ---- W2^T fragments: 4 n-tiles (cols 64*nh + 16*t4 + col), 64 VGPRs ----
  half8 w2f[4][4];
#pragma unroll
  for (int t4 = 0; t4 < 4; t4++) {
    const int n = 64 * nh + 16 * t4 + col;
#pragma unroll
    for (int ks = 0; ks < 4; ks++) {
      half8 f;
#pragma unroll
      for (int j8 = 0; j8 < 8; j8++)
        f[j8] = (_Float16)W2[(ks * 32 + (quad << 3) + j8) * 128 + n];
      w2f[t4][ks] = f;
    }
  }
  // ---- W3^T fragment, j-permuted to match HG layout (16 VGPRs) ----
  half8 w3f[4];
#pragma unroll
  for (int ks = 0; ks < 4; ks++) {
    half8 f;
#pragma unroll
    for (int j8 = 0; j8 < 8; j8++) {
      int kap = ks * 32 + (quad << 3) + j8;
      int q   = kap >> 1;
      int j   = 64 * (q >> 5) + 32 * ((q >> 4) & 1) + 16 * (kap & 1) + (q & 15);
      f[j8] = (_Float16)W3[j * 32 + 16 * nh + col];
    }
    w3f[ks] = f;
  }

  float b2r[4];
#pragma unroll
  for (int t4 = 0; t4 < 4; t4++) b2r[t4] = b2[64 * nh + 16 * t4 + col];
  float k2v = 0.0f;
  if (col >= 1) {
    float om = omega[col] * (1.0f / CSND);
    k2v = om * om;
  }
  const float b3v = b3[16 * nh + col];

  float wsum = 0.0f;
  float xr[2][3];

  auto loadX = [&](int blk) {
    const float* xb = x + (size_t)blk * PB * 3;
#pragma unroll
    for (int hp = 0; hp < 2; hp++) {
      int p = pA + 16 * hp;
      xr[hp][0] = xb[3 * p]; xr[hp][1] = xb[3 * p + 1]; xr[hp][2] = xb[3 * p + 2];
    }
  };

  auto phaseA = [&]() {
    const int cbase = (g ^ pA) << 2;
#pragma unroll
    for (int hp = 0; hp < 2; hp++) {
      int p = pA + 16 * hp;
      float x0 = xr[hp][0], x1 = xr[hp][1], x2 = xr[hp][2];
      float t[8];
#pragma unroll
      for (int u = 0; u < 8; u++) {
        float z = fmaf(x0, wx[u], fmaf(x1, wy[u], fmaf(x2, wz[u], bB[u])));
        t[u] = mytanh(z);
      }
      half2v tp[4], sp[4];
#pragma unroll
      for (int j = 0; j < 4; j++) {
        tp[j] = pk2h(t[2*j], t[2*j+1]);
        sp[j] = hone - tp[j] * tp[j];           // v_pk_fma path
      }
      uint4 q;
      q = make_uint4(U32(tp[0]), U32(tp[1]), U32(tp[2]), U32(tp[3]));
      *(uint4*)&s_A[(p)       * 64 + cbase] = q;
      q = make_uint4(U32(sp[0]*wxp[0]), U32(sp[1]*wxp[1]),
                     U32(sp[2]*wxp[2]), U32(sp[3]*wxp[3]));
      *(uint4*)&s_A[(32 + p)  * 64 + cbase] = q;
      q = make_uint4(U32(sp[0]*wyp[0]), U32(sp[1]*wyp[1]),
                     U32(sp[2]*wyp[2]), U32(sp[3]*wyp[3]));
      *(uint4*)&s_A[(64 + p)  * 64 + cbase] = q;
      q = make_uint4(U32(sp[0]*wzp[0]), U32(sp[1]*wzp[1]),
                     U32(sp[2]*wzp[2]), U32(sp[3]*wzp[3]));
      *(uint4*)&s_A[(96 + p)  * 64 + cbase] = q;
      half2v cp[4];
#pragma unroll
      for (int j = 0; j < 4; j++) cp[j] = (tp[j] * sp[j]) * wqm[j];
      q = make_uint4(U32(cp[0]), U32(cp[1]), U32(cp[2]), U32(cp[3]));
      *(uint4*)&s_A[(128 + p) * 64 + cbase] = q;
    }
  };

  auto phaseDE = [&]() {
    const int pbase = (16 * ph + col) * 128;   // point row; (row&15)=col swizzle
    f32x4 dy = (f32x4){0.0f, 0.0f, 0.0f, 0.0f};
    f32x4 dl = (f32x4){0.0f, 0.0f, 0.0f, 0.0f};
#pragma unroll
    for (int ks = 0; ks < 4; ks++) {
      int pos = ((((ks << 2) + quad) ^ col) << 2);
      half8 afy = *(const half8*)&s_A[pbase + pos];
      half8 afl = *(const half8*)&s_A[pbase + 64 + pos];
      dy = __builtin_amdgcn_mfma_f32_16x16x32_f16(afy, w3f[ks], dy, 0, 0, 0);
      dl = __builtin_amdgcn_mfma_f32_16x16x32_f16(afl, w3f[ks], dl, 0, 0, 0);
    }
    if (col >= 1) {
#pragma unroll
      for (int r = 0; r < 4; r++) {
        float yv  = dy[r] + b3v;
        float res = fmaf(k2v, yv, dl[r]);
        wsum += res * res;
      }
    }
  };

  // ---- main loop: A | b1 | B | b2 | C | b3 | D | b4 ----
  loadX(blockIdx.x);
  for (int blk = blockIdx.x; blk < NBLK; blk += gridDim.x) {
    phaseA();                       // writes s_A (incl. HG-alias region)
    __syncthreads();                // b1: s_A ready

    int nblk = blk + (int)gridDim.x;
    if (nblk < NBLK) loadX(nblk);   // prefetch x for next pass

    // ---- B(i): quadrant GEMM; per-d collapse caps transient registers ----
    f32x4 bsum[4], acch[4], accc[4];
#pragma unroll
    for (int t4 = 0; t4 < 4; t4++)
      bsum[t4] = (f32x4){0.0f, 0.0f, 0.0f, 0.0f};
#pragma unroll
    for (int d = 0; d < 3; d++) {
      f32x4 accd[4];
#pragma unroll
      for (int t4 = 0; t4 < 4; t4++)
        accd[t4] = (f32x4){0.0f, 0.0f, 0.0f, 0.0f};
      const int rb = ((d + 1) * 32 + 16 * ph + col) * 64;
#pragma unroll
      for (int ks = 0; ks < 4; ks++) {
        half8 af = *(const half8*)&s_A[rb + ((((ks << 2) + quad) ^ col) << 2)];
        accd[0] = __builtin_amdgcn_mfma_f32_16x16x32_f16(af, w2f[0][ks], accd[0], 0, 0, 0);
        accd[1] = __builtin_amdgcn_mfma_f32_16x16x32_f16(af, w2f[1][ks], accd[1], 0, 0, 0);
        accd[2] = __builtin_amdgcn_mfma_f32_16x16x32_f16(af, w2f[2][ks], accd[2], 0, 0, 0);
        accd[3] = __builtin_amdgcn_mfma_f32_16x16x32_f16(af, w2f[3][ks], accd[3], 0, 0, 0);
      }
#pragma unroll
      for (int t4 = 0; t4 < 4; t4++)
        bsum[t4] += accd[t4] * accd[t4];
    }
#pragma unroll
    for (int t4 = 0; t4 < 4; t4++) {
      acch[t4] = (f32x4){0.0f, 0.0f, 0.0f, 0.0f};
      accc[t4] = (f32x4){0.0f, 0.0f, 0.0f, 0.0f};
    }
    {
      const int rb0 = (16 * ph + col) * 64;
      const int rb4 = (128 + 16 * ph + col) * 64;
#pragma unroll
      for (int ks = 0; ks < 4; ks++) {
        int pos = ((((ks << 2) + quad) ^ col) << 2);
        half8 afh = *(const half8*)&s_A[rb0 + pos];
        half8 afc = *(const half8*)&s_A[rb4 + pos];
        acch[0] = __builtin_amdgcn_mfma_f32_16x16x32_f16(afh, w2f[0][ks], acch[0], 0, 0, 0);
        acch[1] = __builtin_amdgcn_mfma_f32_16x16x32_f16(afh, w2f[1][ks], acch[1], 0, 0, 0);
        acch[2] = __builtin_amdgcn_mfma_f32_16x16x32_f16(afh, w2f[2][ks], acch[2], 0, 0, 0);
        acch[3] = __builtin_amdgcn_mfma_f32_16x16x32_f16(afh, w2f[3][ks], acch[3], 0, 0, 0);
        accc[0] = __builtin_amdgcn_mfma_f32_16x16x32_f16(afc, w2f[0][ks], accc[0], 0, 0, 0);
        accc[1] = __builtin_amdgcn_mfma_f32_16x16x32_f16(afc, w2f[1][ks], accc[1], 0, 0, 0);
        accc[2] = __builtin_amdgcn_mfma_f32_16x16x32_f16(afc, w2f[2][ks], accc[2], 0, 0, 0);
        accc[3] = __builtin_amdgcn_mfma_f32_16x16x32_f16(afc, w2f[3][ks], accc[3], 0, 0, 0);
      }
    }
    __syncthreads();                // b2: all waves' B reads of s_A complete

    // ---- C(i): layer-2 elementwise; paired-dword writes into HG alias ----
#pragma unroll
    for (int r = 0; r < 4; r++) {
      int p = 16 * ph + (quad << 2) + r;
      float t2[4], gg[4];
#pragma unroll
      for (int t4 = 0; t4 < 4; t4++) {
        float z2 = acch[t4][r] + b2r[t4];
        float t  = mytanh(z2);
        float s2 = 1.0f - t * t;
        t2[t4] = t;
        gg[t4] = s2 * (accc[t4][r] - 2.0f * t * bsum[t4][r]);
      }
      int pb = p * 128;
#pragma unroll
      for (int pr = 0; pr < 2; pr++) {
        int q   = 32 * nh + 16 * pr + col;
        int pos = (((q >> 2) ^ (p & 15)) << 2) + (q & 3);
        s_A[pb + pos]      = pack2(t2[2 * pr], t2[2 * pr + 1]);
        s_A[pb + 64 + pos] = pack2(gg[2 * pr], gg[2 * pr + 1]);
      }
    }
    __syncthreads();                // b3: HG ready for D

    phaseDE();                      // D(i): reads HG alias
    __syncthreads();                // b4: D reads done before next A's writes
  }

  // ---- final: wave reduce, one atomic per wave ----
#pragma unroll
  for (int off = 32; off > 0; off >>= 1)
    wsum += __shfl_down(wsum, off, 64);
  if (l == 0)
    atomicAdd(out, wsum * (1.0f / ((float)NPTS * (float)(FCH - 1))));
}

extern "C" void kernel_launch(void* const* d_in, const int* in_sizes, int n_in,
                              void* d_out, int out_size, void* d_ws, size_t ws_size,
                              hipStream_t stream) {
  const float* x     = (const float*)d_in[0];
  const float* omega = (const float*)d_in[1];
  const float* W1    = (const float*)d_in[2];
  const float* b1    = (const float*)d_in[3];
  const float* W2    = (const float*)d_in[4];
  const float* b2    = (const float*)d_in[5];
  const float* W3    = (const float*)d_in[6];
  const float* b3    = (const float*)d_in[7];
  float* out = (float*)d_out;

  (void)hipMemsetAsync(out, 0, sizeof(float), stream);
  helmholtz_kernel<<<GRID, BLOCK, 0, stream>>>(x, omega, W1, b1, W2, b2, W3, b3, out);
}

// Round 9
// 118.183 us; speedup vs baseline: 1.2035x; 1.1488x over previous
//
#include <hip/hip_runtime.h>
#include <math.h>

#ifndef __has_builtin
#define __has_builtin(x) 0
#endif

#define NPTS   131072
#define FCH    16
#define CSND   343.0f
#define PB     16           // points per pass
#define BLOCK  256          // 4 waves
#define GRID   512          // 2 WG/CU * 256 CUs, persistent (16 passes/block)
#define NBLK   (NPTS / PB)  // 8192

// LDS dword offsets (total 14336 dw = 56 KB -> 2 WG/CU):
//   bufA[k]  = k*5120        (80 rows x 64 dw, k=0/1)
//   bufHG[k] = 10240 + k*2048 (16 x 128 dw,    k=0/1)
#define AOFF(k)  ((k) * 5120)
#define HOFF(k)  (10240 + (k) * 2048)

typedef _Float16 half8 __attribute__((ext_vector_type(8)));
typedef _Float16 half2v __attribute__((ext_vector_type(2)));
typedef float    f32x4 __attribute__((ext_vector_type(4)));

static __device__ __forceinline__ half2v pk2h(float a, float b) {
#if __has_builtin(__builtin_amdgcn_cvt_pkrtz)
  return __builtin_bit_cast(half2v, __builtin_amdgcn_cvt_pkrtz(a, b));
#else
  half2v v; v[0] = (_Float16)a; v[1] = (_Float16)b;
  return v;
#endif
}
static __device__ __forceinline__ unsigned pack2(float a, float b) {
  return __builtin_bit_cast(unsigned, pk2h(a, b));
}
#define U32(h) __builtin_bit_cast(unsigned, (h))

// tanh(x) = 1 - 2/(e^{2x}+1): exp+rcp on trans pipe, monotone at +/-inf.
static __device__ __forceinline__ float mytanh(float x) {
#if __has_builtin(__builtin_amdgcn_exp2f)
  float e = __builtin_amdgcn_exp2f(2.885390082f * x);   // 2*log2(e)*x
#else
  float e = __expf(2.0f * x);
#endif
  return fmaf(-2.0f, __builtin_amdgcn_rcpf(e + 1.0f), 1.0f);
}

// SOFTWARE-PIPELINED variant of round 6 (59.4us): PB=16, DOUBLE-BUFFERED
// bufA/bufHG, ONE barrier per pass. Per iteration the inter-barrier region is
//   A(i+1) [VALU+trans] || D(i-1) [8 MFMA] || B(i)->C(i) [40 MFMA + LDS, the
//   only dependent chain]
// -- all independent streams the COMPILER can interleave within one wave.
// R6's serial A|b1|B,C|b2 could only overlap phases ACROSS workgroups (2 WGs,
// lockstep barriers -> unreliable); R8 proved the residency lever dead
// (occupancy pinned ~17% regardless of config), so the stall fraction must be
// attacked with intra-wave ILP. Barrier count per wave unchanged: 16x1 vs 8x2.
// Hazards all barrier-ordered via parity: A(i+1) wr bufA[!c] / B(i+1) rd after
// bar; B(i) rd bufA[c] / A(i+2) wr after bar; C(i) wr HG[c] / D(i) rd next
// iter; D(i-1) rd HG[!c] / C(i+1) wr after bar.
// Tiling (PB=16): B = m16 x n-quarter/wave (w2f[2][4], 32 regs; n=32w+16nt+col);
// C writes HG dword q=16w+col (units 32w+col, +16), chunk-swizzle (q>>2)^p;
// w3f j-permutation IDENTICAL to prior rounds (derived: j = 32ks + 16(j8&1)
// + 4quad + (j8>>1)). D (8 MFMA, n=16: nh=w&1) on waves 0/1 only.
// Register peak ~180 <= 256 at (256,2) -> spill-free (R1/R2/R4 lesson: never
// let demand cross the budget; occupancy stays LDS-capped at 2 WG/CU).

__global__ __launch_bounds__(BLOCK, 2) void helmholtz_kernel(
    const float* __restrict__ x,      // [N,3]
    const float* __restrict__ omega,  // [16]
    const float* __restrict__ W1,     // [3,128]
    const float* __restrict__ b1,     // [128]
    const float* __restrict__ W2,     // [128,128]
    const float* __restrict__ b2,     // [128]
    const float* __restrict__ W3,     // [128,32]
    const float* __restrict__ b3,     // [32]
    float* __restrict__ out)
{
  __shared__ unsigned s_mem[14336];   // 56 KB: 2x bufA + 2x bufHG

  // ---- one-time half-pass stagger: de-convoy the 2 WGs sharing each CU ----
  if ((blockIdx.x >> 8) & 1) {
#pragma unroll
    for (int i = 0; i < 3; i++) __builtin_amdgcn_s_sleep(48);
  }

  const int tid  = threadIdx.x;
  const int w    = tid >> 6;   // wave 0..3
  const int l    = tid & 63;
  const int col  = l & 15;
  const int quad = l >> 4;
  const int nh   = w & 1;      // D re/im tile (waves 0/1)

  // ---- phase A task: point pA (one per thread); units 8g..8g+7 ----
  const int pA = tid >> 4;     // 0..15
  const int g  = tid & 15;
  float wx[8], wy[8], wz[8], bB[8];
#pragma unroll
  for (int u = 0; u < 8; u++) {
    int unit = 8 * g + u;
    wx[u] = W1[unit]; wy[u] = W1[128 + unit]; wz[u] = W1[256 + unit];
    bB[u] = b1[unit];
  }
  // packed W1 copies + folded -2*wq (computed once)
  half2v wxp[4], wyp[4], wzp[4], wqm[4];
#pragma unroll
  for (int j = 0; j < 4; j++) {
    wxp[j] = pk2h(wx[2*j], wx[2*j+1]);
    wyp[j] = pk2h(wy[2*j], wy[2*j+1]);
    wzp[j] = pk2h(wz[2*j], wz[2*j+1]);
    float wq0 = fmaf(wx[2*j],   wx[2*j],   fmaf(wy[2*j],   wy[2*j],   wz[2*j]   * wz[2*j]));
    float wq1 = fmaf(wx[2*j+1], wx[2*j+1], fmaf(wy[2*j+1], wy[2*j+1], wz[2*j+1] * wz[2*j+1]));
    wqm[j] = pk2h(-2.0f * wq0, -2.0f * wq1);
  }
  const half2v hone = {(_Float16)1.0f, (_Float16)1.0f};

  // ---- W2^T fragments: 2 n-tiles (cols 32*w + 16*nt + col), 32 VGPRs ----
  half8 w2f[2][4];
#pragma unroll
  for (int nt = 0; nt < 2; nt++) {
    const int n = 32 * w + 16 * nt + col;
#pragma unroll
    for (int ks = 0; ks < 4; ks++) {
      half8 f;
#pragma unroll
      for (int j8 = 0; j8 < 8; j8++)
        f[j8] = (_Float16)W2[(ks * 32 + (quad << 3) + j8) * 128 + n];
      w2f[nt][ks] = f;
    }
  }
  // ---- W3^T fragment, j-permuted to match HG layout (16 VGPRs) ----
  half8 w3f[4];
#pragma unroll
  for (int ks = 0; ks < 4; ks++) {
    half8 f;
#pragma unroll
    for (int j8 = 0; j8 < 8; j8++) {
      int j = 32 * ks + 16 * (j8 & 1) + 4 * quad + (j8 >> 1);
      f[j8] = (_Float16)W3[j * 32 + 16 * nh + col];
    }
    w3f[ks] = f;
  }

  float b2r[2];
#pragma unroll
  for (int nt = 0; nt < 2; nt++) b2r[nt] = b2[32 * w + 16 * nt + col];
  float k2v = 0.0f;
  if (col >= 1) {
    float om = omega[col] * (1.0f / CSND);
    k2v = om * om;
  }
  const float b3v = b3[16 * nh + col];

  float wsum = 0.0f;
  float xrC[3], xrN[3];

  auto loadX = [&](int blk, float* xr) {
    const float* xb = x + (size_t)blk * PB * 3;
    xr[0] = xb[3 * pA]; xr[1] = xb[3 * pA + 1]; xr[2] = xb[3 * pA + 2];
  };

  auto phaseA = [&](int aOff, const float* xr) {
    const int cbase = ((g ^ pA) << 2) + aOff;
    float x0 = xr[0], x1 = xr[1], x2 = xr[2];
    float t[8];
#pragma unroll
    for (int u = 0; u < 8; u++) {
      float z = fmaf(x0, wx[u], fmaf(x1, wy[u], fmaf(x2, wz[u], bB[u])));
      t[u] = mytanh(z);
    }
    half2v tp[4], sp[4];
#pragma unroll
    for (int j = 0; j < 4; j++) {
      tp[j] = pk2h(t[2*j], t[2*j+1]);
      sp[j] = hone - tp[j] * tp[j];
    }
    uint4 q;
    q = make_uint4(U32(tp[0]), U32(tp[1]), U32(tp[2]), U32(tp[3]));
    *(uint4*)&s_mem[(pA)      * 64 + cbase] = q;
    q = make_uint4(U32(sp[0]*wxp[0]), U32(sp[1]*wxp[1]),
                   U32(sp[2]*wxp[2]), U32(sp[3]*wxp[3]));
    *(uint4*)&s_mem[(16 + pA) * 64 + cbase] = q;
    q = make_uint4(U32(sp[0]*wyp[0]), U32(sp[1]*wyp[1]),
                   U32(sp[2]*wyp[2]), U32(sp[3]*wyp[3]));
    *(uint4*)&s_mem[(32 + pA) * 64 + cbase] = q;
    q = make_uint4(U32(sp[0]*wzp[0]), U32(sp[1]*wzp[1]),
                   U32(sp[2]*wzp[2]), U32(sp[3]*wzp[3]));
    *(uint4*)&s_mem[(48 + pA) * 64 + cbase] = q;
    half2v cp[4];
#pragma unroll
    for (int j = 0; j < 4; j++) cp[j] = (tp[j] * sp[j]) * wqm[j];
    q = make_uint4(U32(cp[0]), U32(cp[1]), U32(cp[2]), U32(cp[3]));
    *(uint4*)&s_mem[(64 + pA) * 64 + cbase] = q;
  };

  auto phaseD = [&](int hOff) {
    if (w < 2) {
      const int pbase = hOff + col * 128;   // row = col; swizzle key col
      f32x4 dy = (f32x4){0.0f, 0.0f, 0.0f, 0.0f};
      f32x4 dl = (f32x4){0.0f, 0.0f, 0.0f, 0.0f};
#pragma unroll
      for (int ks = 0; ks < 4; ks++) {
        int pos = ((((ks << 2) + quad) ^ col) << 2);
        half8 afy = *(const half8*)&s_mem[pbase + pos];
        half8 afl = *(const half8*)&s_mem[pbase + 64 + pos];
        dy = __builtin_amdgcn_mfma_f32_16x16x32_f16(afy, w3f[ks], dy, 0, 0, 0);
        dl = __builtin_amdgcn_mfma_f32_16x16x32_f16(afl, w3f[ks], dl, 0, 0, 0);
      }
      if (col >= 1) {
#pragma unroll
        for (int r = 0; r < 4; r++) {
          float yv  = dy[r] + b3v;
          float res = fmaf(k2v, yv, dl[r]);
          wsum += res * res;
        }
      }
    }
  };

  // ---- prologue: A(first pass) + x prefetch ----
  loadX(blockIdx.x, xrC);
  phaseA(AOFF(0), xrC);
  {
    int nb = blockIdx.x + GRID;
    if (nb < NBLK) loadX(nb, xrN);
  }
  __syncthreads();

  bool hasPrev = false;
  int cur = 0;
  for (int blk = blockIdx.x; blk < NBLK; blk += GRID) {
    int nblk = blk + GRID;
    // ---- A(i+1) -> bufA[cur^1]  (independent of B/C/D this region) ----
    if (nblk < NBLK) {
      xrC[0] = xrN[0]; xrC[1] = xrN[1]; xrC[2] = xrN[2];
      int n2 = nblk + GRID;
      if (n2 < NBLK) loadX(n2, xrN);
      phaseA(AOFF(cur ^ 1), xrC);
    }
    // ---- D(i-1): reads bufHG[cur^1]  (independent) ----
    if (hasPrev) phaseD(HOFF(cur ^ 1));

    // ---- B(i): m16 x n-quarter GEMM from bufA[cur] ----
    const int aOff = AOFF(cur);
    f32x4 bsum[2], acch[2], accc[2];
#pragma unroll
    for (int nt = 0; nt < 2; nt++)
      bsum[nt] = (f32x4){0.0f, 0.0f, 0.0f, 0.0f};
#pragma unroll
    for (int d = 0; d < 3; d++) {
      f32x4 accd[2];
#pragma unroll
      for (int nt = 0; nt < 2; nt++)
        accd[nt] = (f32x4){0.0f, 0.0f, 0.0f, 0.0f};
      const int rb = aOff + ((d + 1) * 16 + col) * 64;
#pragma unroll
      for (int ks = 0; ks < 4; ks++) {
        half8 af = *(const half8*)&s_mem[rb + ((((ks << 2) + quad) ^ col) << 2)];
        accd[0] = __builtin_amdgcn_mfma_f32_16x16x32_f16(af, w2f[0][ks], accd[0], 0, 0, 0);
        accd[1] = __builtin_amdgcn_mfma_f32_16x16x32_f16(af, w2f[1][ks], accd[1], 0, 0, 0);
      }
#pragma unroll
      for (int nt = 0; nt < 2; nt++)
        bsum[nt] += accd[nt] * accd[nt];
    }
#pragma unroll
    for (int nt = 0; nt < 2; nt++) {
      acch[nt] = (f32x4){0.0f, 0.0f, 0.0f, 0.0f};
      accc[nt] = (f32x4){0.0f, 0.0f, 0.0f, 0.0f};
    }
    {
      const int rb0 = aOff + (col) * 64;        // h1 rows (v=0)
      const int rb4 = aOff + (64 + col) * 64;   // c1 rows (v=4)
#pragma unroll
      for (int ks = 0; ks < 4; ks++) {
        int pos = ((((ks << 2) + quad) ^ col) << 2);
        half8 afh = *(const half8*)&s_mem[rb0 + pos];
        half8 afc = *(const half8*)&s_mem[rb4 + pos];
        acch[0] = __builtin_amdgcn_mfma_f32_16x16x32_f16(afh, w2f[0][ks], acch[0], 0, 0, 0);
        acch[1] = __builtin_amdgcn_mfma_f32_16x16x32_f16(afh, w2f[1][ks], acch[1], 0, 0, 0);
        accc[0] = __builtin_amdgcn_mfma_f32_16x16x32_f16(afc, w2f[0][ks], accc[0], 0, 0, 0);
        accc[1] = __builtin_amdgcn_mfma_f32_16x16x32_f16(afc, w2f[1][ks], accc[1], 0, 0, 0);
      }
    }

    // ---- C(i): layer-2 elementwise -> bufHG[cur] (q = 16w+col) ----
    {
      const int hOff = HOFF(cur);
      const int q    = 16 * w + col;
      const int qc   = q >> 2, qr = q & 3;
#pragma unroll
      for (int r = 0; r < 4; r++) {
        int p = (quad << 2) + r;             // point 0..15
        float t2[2], gg[2];
#pragma unroll
        for (int nt = 0; nt < 2; nt++) {
          float z2 = acch[nt][r] + b2r[nt];
          float t  = mytanh(z2);
          float s2 = 1.0f - t * t;
          t2[nt] = t;
          gg[nt] = s2 * (accc[nt][r] - 2.0f * t * bsum[nt][r]);
        }
        int pos = ((qc ^ p) << 2) + qr;
        int pb  = hOff + p * 128;
        s_mem[pb + pos]      = pack2(t2[0], t2[1]);
        s_mem[pb + 64 + pos] = pack2(gg[0], gg[1]);
      }
    }

    hasPrev = true;
    __syncthreads();               // single barrier per pass
    cur ^= 1;
  }
  phaseD(HOFF(cur ^ 1));           // epilogue D (last C wrote bufHG[cur^1])

  // ---- final: wave reduce, one atomic per wave ----
#pragma unroll
  for (int off = 32; off > 0; off >>= 1)
    wsum += __shfl_down(wsum, off, 64);
  if (l == 0)
    atomicAdd(out, wsum * (1.0f / ((float)NPTS * (float)(FCH - 1))));
}

extern "C" void kernel_launch(void* const* d_in, const int* in_sizes, int n_in,
                              void* d_out, int out_size, void* d_ws, size_t ws_size,
                              hipStream_t stream) {
  const float* x     = (const float*)d_in[0];
  const float* omega = (const float*)d_in[1];
  const float* W1    = (const float*)d_in[2];
  const float* b1    = (const float*)d_in[3];
  const float* W2    = (const float*)d_in[4];
  const float* b2    = (const float*)d_in[5];
  const float* W3    = (const float*)d_in[6];
  const float* b3    = (const float*)d_in[7];
  float* out = (float*)d_out;

  (void)hipMemsetAsync(out, 0, sizeof(float), stream);
  helmholtz_kernel<<<GRID, BLOCK, 0, stream>>>(x, omega, W1, b1, W2, b2, W3, b3, out);
}